// Round 5
// baseline (223.712 us; speedup 1.0000x reference)
//
#include <hip/hip_runtime.h>

#define HW (512*512)

typedef __attribute__((ext_vector_type(8))) short bfrag;   // 8 x bf16
typedef __attribute__((ext_vector_type(4))) float ffrag;   // 4 x f32 acc
typedef __attribute__((ext_vector_type(4))) float fx4;
typedef __attribute__((ext_vector_type(4))) unsigned int ux4;

__device__ __forceinline__ unsigned short f2bf(float f) {
  unsigned int u = __float_as_uint(f);
  u += 0x7fffu + ((u >> 16) & 1u);        // round-to-nearest-even
  return (unsigned short)(u >> 16);
}
__device__ __forceinline__ unsigned int pk2(float a, float b) {
  return (unsigned int)f2bf(a) | ((unsigned int)f2bf(b) << 16);
}

// ---------- Kernel W: pack conv weights into MFMA A-fragment layout --------
// Fragment (ciblk, tap): lane l holds W[co = l&15][ci = ciblk*32 + (l>>4)*8 + j]
__global__ __launch_bounds__(256) void pack_w_k(
    const float* __restrict__ cw, unsigned short* __restrict__ wp) {
  int gid = blockIdx.x * 256 + threadIdx.x;
  if (gid >= 72 * 64) return;
  int fid = gid >> 6, lane = gid & 63;
  int cib = fid / 9, tap = fid - cib * 9;
  int g = lane >> 4, m = lane & 15;
  unsigned short v[8];
#pragma unroll
  for (int j = 0; j < 8; ++j) {
    int ci = cib * 32 + g * 8 + j;
    float f = (m < 8) ? cw[(m * 256 + ci) * 9 + tap] : 0.0f;
    v[j] = f2bf(f);
  }
  *(uint4*)(wp + gid * 8) = *(const uint4*)v;
}

// -------- Pass 1: NCHW f32 -> NHWC bf16 (both sides streaming, no LDS) -----
// 1024 blocks x 256 thr; thread = 1 pixel, loops 32 chunks of 8 ci, 2-deep
// pipelined. Reads: 256B contiguous per plane per instr. Writes: 16B/lane at
// 512B stride -> merged in L2 (same thread fills a 64B line in 4 iters).
__global__ __launch_bounds__(256) void nchw2nhwc_k(
    const float* __restrict__ x, char* __restrict__ nhwc,
    float* __restrict__ zpage) {
  if (blockIdx.x == 0 && threadIdx.x < 64) zpage[threadIdx.x] = 0.0f;
  const int pix = blockIdx.x * 256 + threadIdx.x;
  const float* xp = x + pix;
  char* op = nhwc + (size_t)pix * 512;

#pragma unroll 1
  for (int c = 0; c < 32; c += 2) {
    float a0 = xp[(size_t)(c*8+0)*HW], a1 = xp[(size_t)(c*8+1)*HW];
    float a2 = xp[(size_t)(c*8+2)*HW], a3 = xp[(size_t)(c*8+3)*HW];
    float a4 = xp[(size_t)(c*8+4)*HW], a5 = xp[(size_t)(c*8+5)*HW];
    float a6 = xp[(size_t)(c*8+6)*HW], a7 = xp[(size_t)(c*8+7)*HW];
    float b0 = xp[(size_t)(c*8+8)*HW],  b1 = xp[(size_t)(c*8+9)*HW];
    float b2 = xp[(size_t)(c*8+10)*HW], b3 = xp[(size_t)(c*8+11)*HW];
    float b4 = xp[(size_t)(c*8+12)*HW], b5 = xp[(size_t)(c*8+13)*HW];
    float b6 = xp[(size_t)(c*8+14)*HW], b7 = xp[(size_t)(c*8+15)*HW];
    ux4 oa, ob;
    oa.x = pk2(a0, a1); oa.y = pk2(a2, a3); oa.z = pk2(a4, a5); oa.w = pk2(a6, a7);
    ob.x = pk2(b0, b1); ob.y = pk2(b2, b3); ob.z = pk2(b4, b5); ob.w = pk2(b6, b7);
    *(ux4*)(op + c * 16)        = oa;
    *(ux4*)(op + c * 16 + 16)   = ob;
  }
}

// ------------- Pass 2: 3x3 conv via bf16 MFMA implicit GEMM on NHWC --------
// 32w x 16h tile, 512 thr (8 waves), 512 blocks. LDS [px 612][32ci x bf16]
// (64B per px). Staging: 16B/lane global loads (aligned lines, 0 overfetch)
// -> contiguous ds_write_b128 (conflict-free). Loads(t+1) fly across MFMA(t).
__global__ __launch_bounds__(512, 2) void conv_mfma_k(
    const char* __restrict__ nhwc, const char* __restrict__ zpage,
    const unsigned short* __restrict__ wp, const float* __restrict__ cb,
    float* __restrict__ xc) {
  __shared__ __align__(16) char xs[2448 * 16];           // 39168 B
  const int tid  = threadIdx.x;
  const int wid  = tid >> 6, lane = tid & 63;
  const int gl   = lane >> 4, p = lane & 15;
  const int wcol = wid & 1, hrow = wid >> 1;
  const int bw = blockIdx.x & 15, bh = blockIdx.x >> 4;
  const int w0 = bw * 32, h0 = bh * 16;

  // t-invariant staging descriptors: slot s = tid + k*512; px = s>>2, sub = s&3
  const char* sp[5];
  int adv[5];
#pragma unroll
  for (int k = 0; k < 5; ++k) {
    int s = tid + k * 512;
    int px = s >> 2, sub = s & 3;
    int r = px / 34, cc = px - r * 34;
    int gh = h0 - 1 + r, gw = w0 - 1 + cc;
    bool ok = (s < 2448) && ((unsigned)gh < 512u) && ((unsigned)gw < 512u);
    sp[k]  = ok ? nhwc + (size_t)(gh * 512 + gw) * 512 + sub * 16
                : zpage + sub * 16;
    adv[k] = ok ? 64 : 0;
  }
  const bool w4 = (tid < 400);    // slot tid+2048 exists only for tid<400

  ux4 L0, L1, L2, L3, L4;
#define LOADL                                                   \
  { L0 = *(const ux4*)sp[0]; L1 = *(const ux4*)sp[1];           \
    L2 = *(const ux4*)sp[2]; L3 = *(const ux4*)sp[3];           \
    L4 = *(const ux4*)sp[4];                                    \
    sp[0] += adv[0]; sp[1] += adv[1]; sp[2] += adv[2];          \
    sp[3] += adv[3]; sp[4] += adv[4]; }

  ffrag acc0 = {0,0,0,0}, acc1 = {0,0,0,0}, acc2 = {0,0,0,0}, acc3 = {0,0,0,0};

  LOADL;                          // tile 0 in flight

#pragma unroll 1
  for (int t = 0; t < 8; ++t) {
    if (t) __syncthreads();       // all waves done reading previous tile
    // ds_write tile t (counted vmcnt drains only L0..L4)
    *(ux4*)(xs + tid * 16)         = L0;
    *(ux4*)(xs + tid * 16 + 8192)  = L1;
    *(ux4*)(xs + tid * 16 + 16384) = L2;
    *(ux4*)(xs + tid * 16 + 24576) = L3;
    if (w4) *(ux4*)(xs + tid * 16 + 32768) = L4;
    if (t < 7) LOADL;             // tile t+1 flies across MFMA phase

    // A fragments for this ci-block (L2-resident)
    bfrag a[9];
    const unsigned short* wpt = wp + (size_t)(t * 9) * 512 + lane * 8;
#pragma unroll
    for (int tap = 0; tap < 9; ++tap)
      a[tap] = *(const bfrag*)(wpt + tap * 512);

    __syncthreads();              // tile t staged

    // MFMA phase: 18 ds_read_b128 + 36 MFMA per wave
    const char* rbase = xs + ((hrow * 4) * 34 + wcol * 16 + p) * 64 + gl * 16;
#pragma unroll
    for (int row6 = 0; row6 < 6; ++row6) {
#pragma unroll
      for (int dx = 0; dx < 3; ++dx) {
        bfrag b = *(const bfrag*)(rbase + (row6 * 34 + dx) * 64);
        if (row6 <= 2)
          acc0 = __builtin_amdgcn_mfma_f32_16x16x32_bf16(a[row6*3+dx], b, acc0, 0,0,0);
        if (row6 >= 1 && row6 <= 3)
          acc1 = __builtin_amdgcn_mfma_f32_16x16x32_bf16(a[(row6-1)*3+dx], b, acc1, 0,0,0);
        if (row6 >= 2 && row6 <= 4)
          acc2 = __builtin_amdgcn_mfma_f32_16x16x32_bf16(a[(row6-2)*3+dx], b, acc2, 0,0,0);
        if (row6 >= 3)
          acc3 = __builtin_amdgcn_mfma_f32_16x16x32_bf16(a[(row6-3)*3+dx], b, acc3, 0,0,0);
      }
    }
  }
#undef LOADL

  // epilogue: D col = lane&15 (pixel), row = (lane>>4)*4 + reg (co)
  if (lane < 32) {
    const int wcolp = w0 + wcol * 16 + p;
#pragma unroll
    for (int reg = 0; reg < 4; ++reg) {
      int co = gl * 4 + reg;
      float b = cb[co];
      float* o = xc + co * HW + (h0 + hrow * 4) * 512 + wcolp;
      o[0]    = acc0[reg] + b;
      o[512]  = acc1[reg] + b;
      o[1024] = acc2[reg] + b;
      o[1536] = acc3[reg] + b;
    }
  }
}

// ------------- Kernel B: argmax one-hot -> 8x8 mean pool -> unfold ---------
__global__ __launch_bounds__(256) void argmax_pool_unfold_k(
    const float* __restrict__ xc, float* __restrict__ U) {
  const int lane = threadIdx.x & 63;
  const int wv   = threadIdx.x >> 6;
  const int cell = blockIdx.x * 4 + wv;      // 0..4095
  const int hd = cell >> 6, wd = cell & 63;  // fm coords (64x64)
  const int h = hd * 8 + (lane >> 3), w = wd * 8 + (lane & 7);
  const int pix = h * 512 + w;

  float best = xc[pix];
  int bc = 0;
#pragma unroll
  for (int c = 1; c < 8; ++c) {
    float v = xc[c * HW + pix];
    if (v > best) { best = v; bc = c; }
  }
  float myu = 0.f;
#pragma unroll
  for (int c = 0; c < 8; ++c) {
    unsigned long long mk = __ballot(bc == c);
    if (lane == c) myu = (float)__popcll(mk) * (1.0f / 64.0f);
  }
  if (lane < 8) {
    const int k = (hd & 7) * 8 + (wd & 7);   // kernel element
    const int m = (hd >> 3) * 8 + (wd >> 3); // patch position
    U[lane * 4096 + k * 64 + m] = myu;
  }
}

// ---- Kernel C: att=(A/nz)·U, fold, 1x1 conv, out=corr*x+x, + attn copy ----
__global__ __launch_bounds__(256) void att_fold_corr_k(
    const float* __restrict__ attn, const float* __restrict__ U,
    const float* __restrict__ cw, const float* __restrict__ cb,
    float* __restrict__ out, float* __restrict__ attn_out) {
  __shared__ float Ul[2][4096];
  __shared__ float Ar[4][64];
  const int tid  = threadIdx.x;
  const int lane = tid & 63;
  const int wv   = tid >> 6;
  const int l    = blockIdx.x * 4 + wv;
  const int hq = l >> 6, wq = l & 63;
  const int h = hq * 8 + (lane >> 3), w = wq * 8 + (lane & 7);

  for (int i = tid; i < 1024; i += 256)
    ((fx4*)Ul[0])[i] = ((const fx4*)U)[i];
  __syncthreads();

  float corrv[8];
#pragma unroll 1
  for (int c = 0; c < 8; ++c) {
    if (c < 7)
      for (int i = tid; i < 1024; i += 256)
        ((fx4*)Ul[(c + 1) & 1])[i] = ((const fx4*)(U + (c + 1) * 4096))[i];

    const int aidx = ((c << 12) + l) * 64 + lane;
    float av = attn[aidx];
    attn_out[aidx] = av;                      // output 1: verbatim copy
    unsigned long long nzm = __ballot(av != 0.0f);
    float inv = 1.0f / ((float)__popcll(nzm) + 1e-5f);
    Ar[wv][lane] = av * inv;

    const float* u = Ul[c & 1];
    float s = 0.f;
#pragma unroll
    for (int k = 0; k < 64; ++k)
      s = fmaf(Ar[wv][k], u[k * 64 + lane], s);
    corrv[c] = s;
    __syncthreads();
  }

  const int pix = h * 512 + w;
#pragma unroll
  for (int d = 0; d < 8; ++d) {
    float s = cb[d];
#pragma unroll
    for (int c = 0; c < 8; ++c)
      s = fmaf(corrv[c], cw[d * 8 + c], s);
    float v = out[d * HW + pix];
    out[d * HW + pix] = fmaf(s, v, v);
  }
}

extern "C" void kernel_launch(void* const* d_in, const int* in_sizes, int n_in,
                              void* d_out, int out_size, void* d_ws, size_t ws_size,
                              hipStream_t stream) {
  const float* x    = (const float*)d_in[0];
  const float* attn = (const float*)d_in[1];
  const float* cw   = (const float*)d_in[2];
  const float* cb   = (const float*)d_in[3];
  const float* qw   = (const float*)d_in[4];
  const float* qb   = (const float*)d_in[5];
  float* out = (float*)d_out;

  char* ws = (char*)d_ws;
  unsigned short* wpack = (unsigned short*)ws;             // [0, 72KB)
  char*  nhwc  = ws + 131072;                              // 128 MB
  float* zpage = (float*)(ws + 131072 + 134217728);        // 256 B zeros
  float* U     = (float*)(ws + 131072 + 134217728 + 1024); // 128 KB
  float* xc = out;                                         // x_conv in out[0:2M]

  pack_w_k<<<dim3(18), dim3(256), 0, stream>>>(cw, wpack);
  nchw2nhwc_k<<<dim3(1024), dim3(256), 0, stream>>>(x, nhwc, zpage);
  conv_mfma_k<<<dim3(512), dim3(512), 0, stream>>>((const char*)nhwc,
                                                   (const char*)zpage,
                                                   wpack, cb, xc);
  argmax_pool_unfold_k<<<dim3(1024), dim3(256), 0, stream>>>(xc, U);
  att_fold_corr_k<<<dim3(1024), dim3(256), 0, stream>>>(attn, U, qw, qb,
                                                        out, out + 2097152);
}

// Round 6
// 151.608 us; speedup vs baseline: 1.4756x; 1.4756x over previous
//
#include <hip/hip_runtime.h>

#define HW (512*512)

typedef __attribute__((ext_vector_type(8))) short bfrag;   // 8 x bf16
typedef __attribute__((ext_vector_type(4))) float ffrag;   // 4 x f32 acc
typedef __attribute__((ext_vector_type(4))) float fx4;
typedef __attribute__((ext_vector_type(4))) unsigned int ux4;

__device__ __forceinline__ unsigned short f2bf(float f) {
  unsigned int u = __float_as_uint(f);
  u += 0x7fffu + ((u >> 16) & 1u);        // round-to-nearest-even
  return (unsigned short)(u >> 16);
}
__device__ __forceinline__ unsigned int pk2(float a, float b) {
  return (unsigned int)f2bf(a) | ((unsigned int)f2bf(b) << 16);
}

// ---------- Kernel W: pack conv weights into MFMA A-fragment layout --------
// Fragment (ciblk, tap): lane l holds W[co = l&15][ci = ciblk*32 + (l>>4)*8 + j]
__global__ __launch_bounds__(256) void pack_w_k(
    const float* __restrict__ cw, unsigned short* __restrict__ wp) {
  int gid = blockIdx.x * 256 + threadIdx.x;
  if (gid >= 72 * 64) return;
  int fid = gid >> 6, lane = gid & 63;
  int cib = fid / 9, tap = fid - cib * 9;
  int g = lane >> 4, m = lane & 15;
  unsigned short v[8];
#pragma unroll
  for (int j = 0; j < 8; ++j) {
    int ci = cib * 32 + g * 8 + j;
    float f = (m < 8) ? cw[(m * 256 + ci) * 9 + tap] : 0.0f;
    v[j] = f2bf(f);
  }
  *(uint4*)(wp + gid * 8) = *(const uint4*)v;
}

// ------ Pass 1: NCHW f32 -> [cblk8][sub4][px][16B] bf16, LDS-transposed ----
// Block = 1024 px x 32 ch (one cblk). Reads: full 4KB plane-row runs
// (fx4/lane, lane-contiguous). LDS linear [plane][1024px] f32 (conflict-free
// both phases). Writes: 1KB contiguous per wave store, full 64B lines.
__global__ __launch_bounds__(256) void t32_k(
    const float* __restrict__ x, char* __restrict__ x32,
    float* __restrict__ zpage) {
  __shared__ float lt[2][8][1024];
  const int tid = threadIdx.x;
  if (blockIdx.x == 0 && tid < 64) zpage[tid] = 0.0f;
  const int pxt = blockIdx.x & 255, cblk = blockIdx.x >> 8;
  const int px0 = pxt * 1024;
  const float* xb = x + (size_t)cblk * 32 * HW + px0 + tid * 4;
  char* ob = x32 + (size_t)cblk * (HW * 64) + (size_t)px0 * 16;

  fx4 L[8];
#define TLOAD(c)                                                      \
  { _Pragma("unroll") for (int j = 0; j < 8; ++j)                     \
      L[j] = *(const fx4*)(xb + (size_t)((c) * 8 + j) * HW); }
#define TWRITE(c)                                                     \
  { float* d = &lt[(c) & 1][0][0] + tid * 4;                          \
    _Pragma("unroll") for (int j = 0; j < 8; ++j)                     \
      *(fx4*)(d + j * 1024) = L[j]; }

  TLOAD(0); TWRITE(0); __syncthreads();

#pragma unroll 1
  for (int c = 0; c < 4; ++c) {
    if (c < 3) TLOAD(c + 1);              // next chunk flies over gather
    const float* sbuf = &lt[c & 1][0][0];
    char* oc = ob + (size_t)c * (HW * 16);
#pragma unroll
    for (int s = 0; s < 4; ++s) {
      int px = s * 256 + tid;
      const float* r = sbuf + px;         // lane-stride-1: conflict-free
      ux4 v;
      v.x = pk2(r[0],    r[1024]); v.y = pk2(r[2048], r[3072]);
      v.z = pk2(r[4096], r[5120]); v.w = pk2(r[6144], r[7168]);
      *(ux4*)(oc + (size_t)px * 16) = v;  // wave: 1KB contiguous
    }
    if (c < 3) { TWRITE(c + 1); __syncthreads(); }
  }
#undef TLOAD
#undef TWRITE
}

// ------------- Pass 2: 3x3 conv via bf16 MFMA implicit GEMM ----------------
// Reads [cblk][sub][px][16B]: per t, row runs of 66px x 16B per sub; LDS
// image [px612][32ci x bf16] identical to R5's proven kernel.
__global__ __launch_bounds__(512, 2) void conv_mfma_k(
    const char* __restrict__ x32, const char* __restrict__ zpage,
    const unsigned short* __restrict__ wp, const float* __restrict__ cb,
    float* __restrict__ xc) {
  __shared__ __align__(16) char xs[2448 * 16];           // 39168 B
  const int tid  = threadIdx.x;
  const int wid  = tid >> 6, lane = tid & 63;
  const int gl   = lane >> 4, p = lane & 15;
  const int wcol = wid & 1, hrow = wid >> 1;
  const int bw = blockIdx.x & 15, bh = blockIdx.x >> 4;
  const int w0 = bw * 32, h0 = bh * 16;

  // t-invariant staging descriptors: slot s = tid + k*512; px = s>>2, sub = s&3
  const char* sp[5];
  int adv[5];
#pragma unroll
  for (int k = 0; k < 5; ++k) {
    int s = tid + k * 512;
    int px = s >> 2, sub = s & 3;
    int r = px / 34, cc = px - r * 34;
    int gh = h0 - 1 + r, gw = w0 - 1 + cc;
    bool ok = (s < 2448) && ((unsigned)gh < 512u) && ((unsigned)gw < 512u);
    sp[k]  = ok ? x32 + (size_t)sub * (HW * 16) + (size_t)(gh * 512 + gw) * 16
                : zpage + sub * 16;
    adv[k] = ok ? HW * 64 : 0;            // next cblk
  }
  const bool w4 = (tid < 400);    // slot tid+2048 exists only for tid<400

  ux4 L0, L1, L2, L3, L4;
#define LOADL                                                   \
  { L0 = *(const ux4*)sp[0]; L1 = *(const ux4*)sp[1];           \
    L2 = *(const ux4*)sp[2]; L3 = *(const ux4*)sp[3];           \
    L4 = *(const ux4*)sp[4];                                    \
    sp[0] += adv[0]; sp[1] += adv[1]; sp[2] += adv[2];          \
    sp[3] += adv[3]; sp[4] += adv[4]; }

  ffrag acc0 = {0,0,0,0}, acc1 = {0,0,0,0}, acc2 = {0,0,0,0}, acc3 = {0,0,0,0};

  LOADL;                          // tile 0 in flight

#pragma unroll 1
  for (int t = 0; t < 8; ++t) {
    if (t) __syncthreads();       // all waves done reading previous tile
    *(ux4*)(xs + tid * 16)         = L0;
    *(ux4*)(xs + tid * 16 + 8192)  = L1;
    *(ux4*)(xs + tid * 16 + 16384) = L2;
    *(ux4*)(xs + tid * 16 + 24576) = L3;
    if (w4) *(ux4*)(xs + tid * 16 + 32768) = L4;
    if (t < 7) LOADL;             // tile t+1 flies across MFMA phase

    // A fragments for this ci-block (L2-resident)
    bfrag a[9];
    const unsigned short* wpt = wp + (size_t)(t * 9) * 512 + lane * 8;
#pragma unroll
    for (int tap = 0; tap < 9; ++tap)
      a[tap] = *(const bfrag*)(wpt + tap * 512);

    __syncthreads();              // tile t staged

    // MFMA phase: 18 ds_read_b128 + 36 MFMA per wave
    const char* rbase = xs + ((hrow * 4) * 34 + wcol * 16 + p) * 64 + gl * 16;
#pragma unroll
    for (int row6 = 0; row6 < 6; ++row6) {
#pragma unroll
      for (int dx = 0; dx < 3; ++dx) {
        bfrag b = *(const bfrag*)(rbase + (row6 * 34 + dx) * 64);
        if (row6 <= 2)
          acc0 = __builtin_amdgcn_mfma_f32_16x16x32_bf16(a[row6*3+dx], b, acc0, 0,0,0);
        if (row6 >= 1 && row6 <= 3)
          acc1 = __builtin_amdgcn_mfma_f32_16x16x32_bf16(a[(row6-1)*3+dx], b, acc1, 0,0,0);
        if (row6 >= 2 && row6 <= 4)
          acc2 = __builtin_amdgcn_mfma_f32_16x16x32_bf16(a[(row6-2)*3+dx], b, acc2, 0,0,0);
        if (row6 >= 3)
          acc3 = __builtin_amdgcn_mfma_f32_16x16x32_bf16(a[(row6-3)*3+dx], b, acc3, 0,0,0);
      }
    }
  }
#undef LOADL

  // epilogue: D col = lane&15 (pixel), row = (lane>>4)*4 + reg (co)
  if (lane < 32) {
    const int wcolp = w0 + wcol * 16 + p;
#pragma unroll
    for (int reg = 0; reg < 4; ++reg) {
      int co = gl * 4 + reg;
      float b = cb[co];
      float* o = xc + co * HW + (h0 + hrow * 4) * 512 + wcolp;
      o[0]    = acc0[reg] + b;
      o[512]  = acc1[reg] + b;
      o[1024] = acc2[reg] + b;
      o[1536] = acc3[reg] + b;
    }
  }
}

// ------------- Kernel B: argmax one-hot -> 8x8 mean pool -> unfold ---------
__global__ __launch_bounds__(256) void argmax_pool_unfold_k(
    const float* __restrict__ xc, float* __restrict__ U) {
  const int lane = threadIdx.x & 63;
  const int wv   = threadIdx.x >> 6;
  const int cell = blockIdx.x * 4 + wv;      // 0..4095
  const int hd = cell >> 6, wd = cell & 63;  // fm coords (64x64)
  const int h = hd * 8 + (lane >> 3), w = wd * 8 + (lane & 7);
  const int pix = h * 512 + w;

  float best = xc[pix];
  int bc = 0;
#pragma unroll
  for (int c = 1; c < 8; ++c) {
    float v = xc[c * HW + pix];
    if (v > best) { best = v; bc = c; }
  }
  float myu = 0.f;
#pragma unroll
  for (int c = 0; c < 8; ++c) {
    unsigned long long mk = __ballot(bc == c);
    if (lane == c) myu = (float)__popcll(mk) * (1.0f / 64.0f);
  }
  if (lane < 8) {
    const int k = (hd & 7) * 8 + (wd & 7);   // kernel element
    const int m = (hd >> 3) * 8 + (wd >> 3); // patch position
    U[lane * 4096 + k * 64 + m] = myu;
  }
}

// ---- Kernel C: att=(A/nz)·U, fold, 1x1 conv, out=corr*x+x, + attn copy ----
__global__ __launch_bounds__(256) void att_fold_corr_k(
    const float* __restrict__ attn, const float* __restrict__ U,
    const float* __restrict__ cw, const float* __restrict__ cb,
    float* __restrict__ out, float* __restrict__ attn_out) {
  __shared__ float Ul[2][4096];
  __shared__ float Ar[4][64];
  const int tid  = threadIdx.x;
  const int lane = tid & 63;
  const int wv   = tid >> 6;
  const int l    = blockIdx.x * 4 + wv;
  const int hq = l >> 6, wq = l & 63;
  const int h = hq * 8 + (lane >> 3), w = wq * 8 + (lane & 7);

  for (int i = tid; i < 1024; i += 256)
    ((fx4*)Ul[0])[i] = ((const fx4*)U)[i];
  __syncthreads();

  float corrv[8];
#pragma unroll 1
  for (int c = 0; c < 8; ++c) {
    if (c < 7)
      for (int i = tid; i < 1024; i += 256)
        ((fx4*)Ul[(c + 1) & 1])[i] = ((const fx4*)(U + (c + 1) * 4096))[i];

    const int aidx = ((c << 12) + l) * 64 + lane;
    float av = attn[aidx];
    attn_out[aidx] = av;                      // output 1: verbatim copy
    unsigned long long nzm = __ballot(av != 0.0f);
    float inv = 1.0f / ((float)__popcll(nzm) + 1e-5f);
    Ar[wv][lane] = av * inv;

    const float* u = Ul[c & 1];
    float s = 0.f;
#pragma unroll
    for (int k = 0; k < 64; ++k)
      s = fmaf(Ar[wv][k], u[k * 64 + lane], s);
    corrv[c] = s;
    __syncthreads();
  }

  const int pix = h * 512 + w;
#pragma unroll
  for (int d = 0; d < 8; ++d) {
    float s = cb[d];
#pragma unroll
    for (int c = 0; c < 8; ++c)
      s = fmaf(corrv[c], cw[d * 8 + c], s);
    float v = out[d * HW + pix];
    out[d * HW + pix] = fmaf(s, v, v);
  }
}

extern "C" void kernel_launch(void* const* d_in, const int* in_sizes, int n_in,
                              void* d_out, int out_size, void* d_ws, size_t ws_size,
                              hipStream_t stream) {
  const float* x    = (const float*)d_in[0];
  const float* attn = (const float*)d_in[1];
  const float* cw   = (const float*)d_in[2];
  const float* cb   = (const float*)d_in[3];
  const float* qw   = (const float*)d_in[4];
  const float* qb   = (const float*)d_in[5];
  float* out = (float*)d_out;

  char* ws = (char*)d_ws;
  unsigned short* wpack = (unsigned short*)ws;             // [0, 72KB)
  char*  x32   = ws + 131072;                              // 128 MB
  float* zpage = (float*)(ws + 131072 + 134217728);        // 256 B zeros
  float* U     = (float*)(ws + 131072 + 134217728 + 1024); // 128 KB
  float* xc = out;                                         // x_conv in out[0:2M]

  pack_w_k<<<dim3(18), dim3(256), 0, stream>>>(cw, wpack);
  t32_k<<<dim3(2048), dim3(256), 0, stream>>>(x, x32, zpage);
  conv_mfma_k<<<dim3(512), dim3(512), 0, stream>>>((const char*)x32,
                                                   (const char*)zpage,
                                                   wpack, cb, xc);
  argmax_pool_unfold_k<<<dim3(1024), dim3(256), 0, stream>>>(xc, U);
  att_fold_corr_k<<<dim3(1024), dim3(256), 0, stream>>>(attn, U, qw, qb,
                                                        out, out + 2097152);
}

// Round 7
// 143.522 us; speedup vs baseline: 1.5587x; 1.0563x over previous
//
#include <hip/hip_runtime.h>

#define HW (512*512)

typedef __attribute__((ext_vector_type(8))) short bfrag;   // 8 x bf16
typedef __attribute__((ext_vector_type(4))) float ffrag;   // 4 x f32 acc
typedef __attribute__((ext_vector_type(4))) float fx4;
typedef __attribute__((ext_vector_type(4))) unsigned int ux4;

__device__ __forceinline__ unsigned short f2bf(float f) {
  unsigned int u = __float_as_uint(f);
  u += 0x7fffu + ((u >> 16) & 1u);        // round-to-nearest-even
  return (unsigned short)(u >> 16);
}
__device__ __forceinline__ unsigned int pk2(float a, float b) {
  return (unsigned int)f2bf(a) | ((unsigned int)f2bf(b) << 16);
}

// ---------- Kernel W: pack conv weights into MFMA A-fragment layout --------
// Fragment (ciblk, tap): lane l holds W[co = l&15][ci = ciblk*32 + (l>>4)*8 + j]
__global__ __launch_bounds__(256) void pack_w_k(
    const float* __restrict__ cw, unsigned short* __restrict__ wp) {
  int gid = blockIdx.x * 256 + threadIdx.x;
  if (gid >= 72 * 64) return;
  int fid = gid >> 6, lane = gid & 63;
  int cib = fid / 9, tap = fid - cib * 9;
  int g = lane >> 4, m = lane & 15;
  unsigned short v[8];
#pragma unroll
  for (int j = 0; j < 8; ++j) {
    int ci = cib * 32 + g * 8 + j;
    float f = (m < 8) ? cw[(m * 256 + ci) * 9 + tap] : 0.0f;
    v[j] = f2bf(f);
  }
  *(uint4*)(wp + gid * 8) = *(const uint4*)v;
}

// ---- Pass 1: NCHW f32 -> x32[cblk][px][64B] (32ch interleaved per px) -----
// Block = 512 px x 32 ch. Reads: 1KB contiguous run per wave-instr (fx4/lane).
// bf16-pack BEFORE LDS (33KB -> 4 blocks/CU, 1 barrier). Gather: 32 ds_read
// per thread, 2-way banks (free). Stores: 1KB contiguous full lines.
__global__ __launch_bounds__(256) void t32_k(
    const float* __restrict__ x, char* __restrict__ x32,
    float* __restrict__ zpage) {
  __shared__ unsigned int lt[16][516];             // pad 516: gather 2-way
  const int tid = threadIdx.x;
  if (blockIdx.x == 0 && tid < 64) zpage[tid] = 0.0f;
  const int g = blockIdx.x & 511;                  // px-group of 512
  const int cblk = blockIdx.x >> 9;                // 0..7
  const int jbase = tid >> 7;                      // 0 or 1
  const int px4 = (tid & 127) * 4;
  const float* xb = x + (size_t)cblk * 32 * HW + g * 512 + px4;

  fx4 A[8], Bv[8];
#pragma unroll
  for (int jj = 0; jj < 8; ++jj) {
    int j = jbase + jj * 2;
    A[jj]  = *(const fx4*)(xb + (size_t)(2 * j)     * HW);
    Bv[jj] = *(const fx4*)(xb + (size_t)(2 * j + 1) * HW);
  }
#pragma unroll
  for (int jj = 0; jj < 8; ++jj) {
    int j = jbase + jj * 2;
    ux4 v;
    v.x = pk2(A[jj][0], Bv[jj][0]);
    v.y = pk2(A[jj][1], Bv[jj][1]);
    v.z = pk2(A[jj][2], Bv[jj][2]);
    v.w = pk2(A[jj][3], Bv[jj][3]);
    *(ux4*)(&lt[j][px4]) = v;                      // stride-4-word: clean
  }
  __syncthreads();

  const int w = tid >> 6, l = tid & 63;
  const int sub = l & 3, a = l >> 2;
  char* ob = x32 + (size_t)cblk * (HW * 64) + (size_t)g * 32768;
#pragma unroll
  for (int i = 0; i < 8; ++i) {
    int px = (w * 8 + i) * 16 + a;
    ux4 v;
    v.x = lt[sub * 4 + 0][px]; v.y = lt[sub * 4 + 1][px];
    v.z = lt[sub * 4 + 2][px]; v.w = lt[sub * 4 + 3][px];
    *(ux4*)(ob + (size_t)(w * 8 + i) * 1024 + l * 16) = v;  // 1KB/wave-instr
  }
}

// ------------- Pass 2: 3x3 conv via bf16 MFMA implicit GEMM ----------------
// Reads x32[cblk][px][64B]: lanes fully contiguous -> 1KB runs (R5 fast path).
__global__ __launch_bounds__(512, 2) void conv_mfma_k(
    const char* __restrict__ x32, const char* __restrict__ zpage,
    const unsigned short* __restrict__ wp, const float* __restrict__ cb,
    float* __restrict__ xc) {
  __shared__ __align__(16) char xs[2448 * 16];           // 39168 B
  const int tid  = threadIdx.x;
  const int wid  = tid >> 6, lane = tid & 63;
  const int gl   = lane >> 4, p = lane & 15;
  const int wcol = wid & 1, hrow = wid >> 1;
  const int bw = blockIdx.x & 15, bh = blockIdx.x >> 4;
  const int w0 = bw * 32, h0 = bh * 16;

  // t-invariant staging descriptors: slot s = tid + k*512; px = s>>2, sub = s&3
  const char* sp[5];
  int adv[5];
#pragma unroll
  for (int k = 0; k < 5; ++k) {
    int s = tid + k * 512;
    int px = s >> 2, sub = s & 3;
    int r = px / 34, cc = px - r * 34;
    int gh = h0 - 1 + r, gw = w0 - 1 + cc;
    bool ok = (s < 2448) && ((unsigned)gh < 512u) && ((unsigned)gw < 512u);
    sp[k]  = ok ? x32 + (size_t)(gh * 512 + gw) * 64 + sub * 16
                : zpage + sub * 16;
    adv[k] = ok ? HW * 64 : 0;            // next cblk
  }
  const bool w4 = (tid < 400);    // slot tid+2048 exists only for tid<400

  ux4 L0, L1, L2, L3, L4;
#define LOADL                                                   \
  { L0 = *(const ux4*)sp[0]; L1 = *(const ux4*)sp[1];           \
    L2 = *(const ux4*)sp[2]; L3 = *(const ux4*)sp[3];           \
    L4 = *(const ux4*)sp[4];                                    \
    sp[0] += adv[0]; sp[1] += adv[1]; sp[2] += adv[2];          \
    sp[3] += adv[3]; sp[4] += adv[4]; }

  ffrag acc0 = {0,0,0,0}, acc1 = {0,0,0,0}, acc2 = {0,0,0,0}, acc3 = {0,0,0,0};

  LOADL;                          // tile 0 in flight

#pragma unroll 1
  for (int t = 0; t < 8; ++t) {
    if (t) __syncthreads();       // all waves done reading previous tile
    *(ux4*)(xs + tid * 16)         = L0;
    *(ux4*)(xs + tid * 16 + 8192)  = L1;
    *(ux4*)(xs + tid * 16 + 16384) = L2;
    *(ux4*)(xs + tid * 16 + 24576) = L3;
    if (w4) *(ux4*)(xs + tid * 16 + 32768) = L4;
    if (t < 7) LOADL;             // tile t+1 flies across MFMA phase

    // A fragments for this ci-block (L2-resident)
    bfrag a[9];
    const unsigned short* wpt = wp + (size_t)(t * 9) * 512 + lane * 8;
#pragma unroll
    for (int tap = 0; tap < 9; ++tap)
      a[tap] = *(const bfrag*)(wpt + tap * 512);

    __syncthreads();              // tile t staged

    // MFMA phase: 18 ds_read_b128 + 36 MFMA per wave
    const char* rbase = xs + ((hrow * 4) * 34 + wcol * 16 + p) * 64 + gl * 16;
#pragma unroll
    for (int row6 = 0; row6 < 6; ++row6) {
#pragma unroll
      for (int dx = 0; dx < 3; ++dx) {
        bfrag b = *(const bfrag*)(rbase + (row6 * 34 + dx) * 64);
        if (row6 <= 2)
          acc0 = __builtin_amdgcn_mfma_f32_16x16x32_bf16(a[row6*3+dx], b, acc0, 0,0,0);
        if (row6 >= 1 && row6 <= 3)
          acc1 = __builtin_amdgcn_mfma_f32_16x16x32_bf16(a[(row6-1)*3+dx], b, acc1, 0,0,0);
        if (row6 >= 2 && row6 <= 4)
          acc2 = __builtin_amdgcn_mfma_f32_16x16x32_bf16(a[(row6-2)*3+dx], b, acc2, 0,0,0);
        if (row6 >= 3)
          acc3 = __builtin_amdgcn_mfma_f32_16x16x32_bf16(a[(row6-3)*3+dx], b, acc3, 0,0,0);
      }
    }
  }
#undef LOADL

  // epilogue: D col = lane&15 (pixel), row = (lane>>4)*4 + reg (co)
  if (lane < 32) {
    const int wcolp = w0 + wcol * 16 + p;
#pragma unroll
    for (int reg = 0; reg < 4; ++reg) {
      int co = gl * 4 + reg;
      float b = cb[co];
      float* o = xc + co * HW + (h0 + hrow * 4) * 512 + wcolp;
      o[0]    = acc0[reg] + b;
      o[512]  = acc1[reg] + b;
      o[1024] = acc2[reg] + b;
      o[1536] = acc3[reg] + b;
    }
  }
}

// ------------- Kernel B: argmax one-hot -> 8x8 mean pool -> unfold ---------
__global__ __launch_bounds__(256) void argmax_pool_unfold_k(
    const float* __restrict__ xc, float* __restrict__ U) {
  const int lane = threadIdx.x & 63;
  const int wv   = threadIdx.x >> 6;
  const int cell = blockIdx.x * 4 + wv;      // 0..4095
  const int hd = cell >> 6, wd = cell & 63;  // fm coords (64x64)
  const int h = hd * 8 + (lane >> 3), w = wd * 8 + (lane & 7);
  const int pix = h * 512 + w;

  float best = xc[pix];
  int bc = 0;
#pragma unroll
  for (int c = 1; c < 8; ++c) {
    float v = xc[c * HW + pix];
    if (v > best) { best = v; bc = c; }
  }
  float myu = 0.f;
#pragma unroll
  for (int c = 0; c < 8; ++c) {
    unsigned long long mk = __ballot(bc == c);
    if (lane == c) myu = (float)__popcll(mk) * (1.0f / 64.0f);
  }
  if (lane < 8) {
    const int k = (hd & 7) * 8 + (wd & 7);   // kernel element
    const int m = (hd >> 3) * 8 + (wd >> 3); // patch position
    U[lane * 4096 + k * 64 + m] = myu;
  }
}

// ---- Kernel C: att=(A/nz)·U, fold, 1x1 conv, out=corr*x+x, + attn copy ----
__global__ __launch_bounds__(256) void att_fold_corr_k(
    const float* __restrict__ attn, const float* __restrict__ U,
    const float* __restrict__ cw, const float* __restrict__ cb,
    float* __restrict__ out, float* __restrict__ attn_out) {
  __shared__ float Ul[2][4096];
  __shared__ float Ar[4][64];
  const int tid  = threadIdx.x;
  const int lane = tid & 63;
  const int wv   = tid >> 6;
  const int l    = blockIdx.x * 4 + wv;
  const int hq = l >> 6, wq = l & 63;
  const int h = hq * 8 + (lane >> 3), w = wq * 8 + (lane & 7);

  for (int i = tid; i < 1024; i += 256)
    ((fx4*)Ul[0])[i] = ((const fx4*)U)[i];
  __syncthreads();

  float corrv[8];
#pragma unroll 1
  for (int c = 0; c < 8; ++c) {
    if (c < 7)
      for (int i = tid; i < 1024; i += 256)
        ((fx4*)Ul[(c + 1) & 1])[i] = ((const fx4*)(U + (c + 1) * 4096))[i];

    const int aidx = ((c << 12) + l) * 64 + lane;
    float av = attn[aidx];
    attn_out[aidx] = av;                      // output 1: verbatim copy
    unsigned long long nzm = __ballot(av != 0.0f);
    float inv = 1.0f / ((float)__popcll(nzm) + 1e-5f);
    Ar[wv][lane] = av * inv;

    const float* u = Ul[c & 1];
    float s = 0.f;
#pragma unroll
    for (int k = 0; k < 64; ++k)
      s = fmaf(Ar[wv][k], u[k * 64 + lane], s);
    corrv[c] = s;
    __syncthreads();
  }

  const int pix = h * 512 + w;
#pragma unroll
  for (int d = 0; d < 8; ++d) {
    float s = cb[d];
#pragma unroll
    for (int c = 0; c < 8; ++c)
      s = fmaf(corrv[c], cw[d * 8 + c], s);
    float v = out[d * HW + pix];
    out[d * HW + pix] = fmaf(s, v, v);
  }
}

extern "C" void kernel_launch(void* const* d_in, const int* in_sizes, int n_in,
                              void* d_out, int out_size, void* d_ws, size_t ws_size,
                              hipStream_t stream) {
  const float* x    = (const float*)d_in[0];
  const float* attn = (const float*)d_in[1];
  const float* cw   = (const float*)d_in[2];
  const float* cb   = (const float*)d_in[3];
  const float* qw   = (const float*)d_in[4];
  const float* qb   = (const float*)d_in[5];
  float* out = (float*)d_out;

  char* ws = (char*)d_ws;
  unsigned short* wpack = (unsigned short*)ws;             // [0, 72KB)
  char*  x32   = ws + 131072;                              // 128 MB
  float* zpage = (float*)(ws + 131072 + 134217728);        // 256 B zeros
  float* U     = (float*)(ws + 131072 + 134217728 + 1024); // 128 KB
  float* xc = out;                                         // x_conv in out[0:2M]

  pack_w_k<<<dim3(18), dim3(256), 0, stream>>>(cw, wpack);
  t32_k<<<dim3(4096), dim3(256), 0, stream>>>(x, x32, zpage);
  conv_mfma_k<<<dim3(512), dim3(512), 0, stream>>>((const char*)x32,
                                                   (const char*)zpage,
                                                   wpack, cb, xc);
  argmax_pool_unfold_k<<<dim3(1024), dim3(256), 0, stream>>>(xc, U);
  att_fold_corr_k<<<dim3(1024), dim3(256), 0, stream>>>(attn, U, qw, qb,
                                                        out, out + 2097152);
}

// Round 8
// 115.395 us; speedup vs baseline: 1.9387x; 1.2438x over previous
//
#include <hip/hip_runtime.h>

#define HW (512*512)

typedef __attribute__((ext_vector_type(8))) short bfrag;   // 8 x bf16
typedef __attribute__((ext_vector_type(4))) float ffrag;   // 4 x f32 acc
typedef __attribute__((ext_vector_type(4))) float fx4;
typedef __attribute__((ext_vector_type(4))) unsigned int ux4;
typedef __attribute__((ext_vector_type(2))) unsigned int ux2;

__device__ __forceinline__ unsigned short f2bf(float f) {
  unsigned int u = __float_as_uint(f);
  u += 0x7fffu + ((u >> 16) & 1u);        // round-to-nearest-even
  return (unsigned short)(u >> 16);
}
__device__ __forceinline__ unsigned int pk2(float a, float b) {
  return (unsigned int)f2bf(a) | ((unsigned int)f2bf(b) << 16);
}

// ---------- Kernel W: pack conv weights, taps folded into K ----------------
// Fragment fid = t*3 + m (t = ci8-block 0..31, m = tap-quad 0..2).
// K = 32 = 4 taps x 8 ci: k = q*8 + j -> tap = 4m+q, ci = t*8 + j.
// lane l: q = l>>4, co = l&15. tap >= 9 or co >= 8 -> 0.
__global__ __launch_bounds__(256) void pack_w_k(
    const float* __restrict__ cw, unsigned short* __restrict__ wp) {
  int gid = blockIdx.x * 256 + threadIdx.x;
  if (gid >= 96 * 64) return;
  int fid = gid >> 6, lane = gid & 63;
  int t = fid / 3, m = fid - t * 3;
  int q = lane >> 4, co = lane & 15;
  int tap = 4 * m + q;
  unsigned short v[8];
#pragma unroll
  for (int j = 0; j < 8; ++j) {
    int ci = t * 8 + j;
    float f = (co < 8 && tap < 9) ? cw[(co * 256 + ci) * 9 + tap] : 0.0f;
    v[j] = f2bf(f);
  }
  *(uint4*)(wp + gid * 8) = *(const uint4*)v;
}

// -------------- Fused 3x3 conv: NCHW read -> bf16 MFMA, no transpose -------
// Block = 256px x 2 rows (512 blocks = 2/CU), 512 thr. Per t (8 ci):
// stage 4 rows x 256px x 8ci as bf16 into LDS [4][260][16B]; reads are 1KB
// contiguous runs. 3 MFMA (K=32=4taps x 8ci) per 16px tile. T14 staging.
constexpr int RS8 = 4160;   // 260 px * 16 B

__global__ __launch_bounds__(512, 4) void conv_fused_k(
    const float* __restrict__ x, const unsigned short* __restrict__ wp,
    const float* __restrict__ cb, float* __restrict__ xc) {
  __shared__ __align__(16) char xs[4 * RS8];     // 16640 B
  const int tid  = threadIdx.x;
  const int wid  = tid >> 6, lane = tid & 63;
  const int q    = lane >> 4, p = lane & 15;
  const int quad = wid & 3, ro = wid >> 2;

  // XCD-swizzled placement: adjacent strips share an XCD's L2 (halo reuse)
  const int bid   = blockIdx.x;
  const int strip = (bid & 7) * 32 + (bid >> 4);
  const int half  = (bid >> 3) & 1;
  const int h0 = strip * 2, w0 = half * 256;

  // ---- interior staging descriptors: unit = tid>>1, plane-half = tid&1 ----
  const int su = tid >> 1, srow = su >> 6, sc = su & 63;
  const int h4 = tid & 1;
  const int sgh = h0 - 1 + srow;
  const bool sok = (unsigned)sgh < 512u;
  const float* sbase = x + (size_t)(h4 * 4) * HW
                         + (sok ? sgh : 0) * 512 + w0 + sc * 4;
  int swb[4];
#pragma unroll
  for (int j = 0; j < 4; ++j)
    swb[j] = srow * RS8 + (sc * 4 + 1 + j) * 16 + h4 * 8;

  // ---- halo-column descriptors (tid 504..511: 4 rows x 2 cols) ----
  const int hs = tid & 7;
  const int hrow = hs >> 1, he = hs & 1;
  const int hgh = h0 - 1 + hrow;
  const int hgpx = w0 + (he ? 256 : -1);
  const bool hok = (tid >= 504) && ((unsigned)hgh < 512u) &&
                   ((unsigned)hgpx < 512u);
  const float* hbase = x + (hok ? (hgh * 512 + hgpx) : 0);
  const int hwb = hrow * RS8 + (he ? 257 : 0) * 16;

  // ---- per-m LDS read offsets: tap = 4m+q (clamped), dy = tap/3 ----
  int mroff[3];
#pragma unroll
  for (int m = 0; m < 3; ++m) {
    int tap = 4 * m + q; if (tap > 8) tap = 8;
    int dy = (tap * 11) >> 5;
    int dx = tap - 3 * dy;
    mroff[m] = dy * RS8 + dx * 16;
  }
  const int rbase = ro * RS8 + (quad * 64 + p) * 16;

  fx4 S[4]; float Hv[8];

#define ISSUE(t)                                                          \
  { const float* sp_ = sbase + (size_t)((t) * 8) * HW;                    \
    S[0] = *(const fx4*)(sp_);                                            \
    S[1] = *(const fx4*)(sp_ + (size_t)HW);                               \
    S[2] = *(const fx4*)(sp_ + 2 * (size_t)HW);                           \
    S[3] = *(const fx4*)(sp_ + 3 * (size_t)HW);                           \
    if (tid >= 504) {                                                     \
      const float* hp_ = hbase + (size_t)((t) * 8) * HW;                  \
      _Pragma("unroll") for (int i_ = 0; i_ < 8; ++i_)                    \
        Hv[i_] = hok ? hp_[(size_t)i_ * HW] : 0.0f;                       \
    } }

#define WRITE()                                                           \
  { _Pragma("unroll") for (int j_ = 0; j_ < 4; ++j_) {                    \
      ux2 v_;                                                             \
      v_.x = pk2(S[0][j_], S[1][j_]);                                     \
      v_.y = pk2(S[2][j_], S[3][j_]);                                     \
      if (!sok) { v_.x = 0u; v_.y = 0u; }                                 \
      *(ux2*)(xs + swb[j_]) = v_;                                         \
    }                                                                     \
    if (tid >= 504) {                                                     \
      ux4 h_;                                                             \
      h_.x = pk2(Hv[0], Hv[1]); h_.y = pk2(Hv[2], Hv[3]);                 \
      h_.z = pk2(Hv[4], Hv[5]); h_.w = pk2(Hv[6], Hv[7]);                 \
      *(ux4*)(xs + hwb) = h_;                                             \
    } }

  ffrag acc[4];
#pragma unroll
  for (int i = 0; i < 4; ++i) acc[i] = ffrag{0.f, 0.f, 0.f, 0.f};

  ISSUE(0);
  WRITE();
  __syncthreads();

#pragma unroll 1
  for (int t = 0; t < 32; ++t) {
    // A fragments first (their vmcnt wait won't drain staging loads)
    const unsigned short* wpt = wp + (size_t)(t * 3) * 512 + lane * 8;
    bfrag a0 = *(const bfrag*)(wpt);
    bfrag a1 = *(const bfrag*)(wpt + 512);
    bfrag a2 = *(const bfrag*)(wpt + 1024);

    if (t < 31) ISSUE(t + 1);     // next ci-block flies across MFMA phase

    // 12 ds_read_b128 + 12 MFMA per wave
#pragma unroll
    for (int kk = 0; kk < 4; ++kk) {
      const char* rb = xs + rbase + kk * 256;
      bfrag b0 = *(const bfrag*)(rb + mroff[0]);
      acc[kk] = __builtin_amdgcn_mfma_f32_16x16x32_bf16(a0, b0, acc[kk], 0, 0, 0);
      bfrag b1 = *(const bfrag*)(rb + mroff[1]);
      acc[kk] = __builtin_amdgcn_mfma_f32_16x16x32_bf16(a1, b1, acc[kk], 0, 0, 0);
      bfrag b2 = *(const bfrag*)(rb + mroff[2]);
      acc[kk] = __builtin_amdgcn_mfma_f32_16x16x32_bf16(a2, b2, acc[kk], 0, 0, 0);
    }

    __syncthreads();              // all waves done reading tile t
    if (t < 31) {
      WRITE();                    // vmcnt drain lands after compute
      __syncthreads();
    }
  }
#undef ISSUE
#undef WRITE

  // epilogue: D col = lane&15 (px), row = q*4 + reg (co, 0..7 valid)
  if (lane < 32) {
    const int orow = h0 + ro;
    const int opx  = w0 + quad * 64 + p;
#pragma unroll
    for (int kk = 0; kk < 4; ++kk)
#pragma unroll
      for (int reg = 0; reg < 4; ++reg) {
        int co = q * 4 + reg;
        xc[co * HW + orow * 512 + opx + kk * 16] = acc[kk][reg] + cb[co];
      }
  }
}

// ------------- Kernel B: argmax one-hot -> 8x8 mean pool -> unfold ---------
__global__ __launch_bounds__(256) void argmax_pool_unfold_k(
    const float* __restrict__ xc, float* __restrict__ U) {
  const int lane = threadIdx.x & 63;
  const int wv   = threadIdx.x >> 6;
  const int cell = blockIdx.x * 4 + wv;      // 0..4095
  const int hd = cell >> 6, wd = cell & 63;  // fm coords (64x64)
  const int h = hd * 8 + (lane >> 3), w = wd * 8 + (lane & 7);
  const int pix = h * 512 + w;

  float best = xc[pix];
  int bc = 0;
#pragma unroll
  for (int c = 1; c < 8; ++c) {
    float v = xc[c * HW + pix];
    if (v > best) { best = v; bc = c; }
  }
  float myu = 0.f;
#pragma unroll
  for (int c = 0; c < 8; ++c) {
    unsigned long long mk = __ballot(bc == c);
    if (lane == c) myu = (float)__popcll(mk) * (1.0f / 64.0f);
  }
  if (lane < 8) {
    const int k = (hd & 7) * 8 + (wd & 7);   // kernel element
    const int m = (hd >> 3) * 8 + (wd >> 3); // patch position
    U[lane * 4096 + k * 64 + m] = myu;
  }
}

// ---- Kernel C: att=(A/nz)·U, fold, 1x1 conv, out=corr*x+x, + attn copy ----
__global__ __launch_bounds__(256) void att_fold_corr_k(
    const float* __restrict__ attn, const float* __restrict__ U,
    const float* __restrict__ cw, const float* __restrict__ cb,
    float* __restrict__ out, float* __restrict__ attn_out) {
  __shared__ float Ul[2][4096];
  __shared__ float Ar[4][64];
  const int tid  = threadIdx.x;
  const int lane = tid & 63;
  const int wv   = tid >> 6;
  const int l    = blockIdx.x * 4 + wv;
  const int hq = l >> 6, wq = l & 63;
  const int h = hq * 8 + (lane >> 3), w = wq * 8 + (lane & 7);

  for (int i = tid; i < 1024; i += 256)
    ((fx4*)Ul[0])[i] = ((const fx4*)U)[i];
  __syncthreads();

  float corrv[8];
#pragma unroll 1
  for (int c = 0; c < 8; ++c) {
    if (c < 7)
      for (int i = tid; i < 1024; i += 256)
        ((fx4*)Ul[(c + 1) & 1])[i] = ((const fx4*)(U + (c + 1) * 4096))[i];

    const int aidx = ((c << 12) + l) * 64 + lane;
    float av = attn[aidx];
    attn_out[aidx] = av;                      // output 1: verbatim copy
    unsigned long long nzm = __ballot(av != 0.0f);
    float inv = 1.0f / ((float)__popcll(nzm) + 1e-5f);
    Ar[wv][lane] = av * inv;

    const float* u = Ul[c & 1];
    float s = 0.f;
#pragma unroll
    for (int k = 0; k < 64; ++k)
      s = fmaf(Ar[wv][k], u[k * 64 + lane], s);
    corrv[c] = s;
    __syncthreads();
  }

  const int pix = h * 512 + w;
#pragma unroll
  for (int d = 0; d < 8; ++d) {
    float s = cb[d];
#pragma unroll
    for (int c = 0; c < 8; ++c)
      s = fmaf(corrv[c], cw[d * 8 + c], s);
    float v = out[d * HW + pix];
    out[d * HW + pix] = fmaf(s, v, v);
  }
}

extern "C" void kernel_launch(void* const* d_in, const int* in_sizes, int n_in,
                              void* d_out, int out_size, void* d_ws, size_t ws_size,
                              hipStream_t stream) {
  const float* x    = (const float*)d_in[0];
  const float* attn = (const float*)d_in[1];
  const float* cw   = (const float*)d_in[2];
  const float* cb   = (const float*)d_in[3];
  const float* qw   = (const float*)d_in[4];
  const float* qb   = (const float*)d_in[5];
  float* out = (float*)d_out;

  char* ws = (char*)d_ws;
  unsigned short* wpack = (unsigned short*)ws;   // 96 frags * 1KB = 96 KB
  float* U = (float*)(ws + 98304);               // 128 KB
  float* xc = out;                               // x_conv lives in out[0:2M]

  pack_w_k<<<dim3(24), dim3(256), 0, stream>>>(cw, wpack);
  conv_fused_k<<<dim3(512), dim3(512), 0, stream>>>(x, wpack, cb, xc);
  argmax_pool_unfold_k<<<dim3(1024), dim3(256), 0, stream>>>(xc, U);
  att_fold_corr_k<<<dim3(1024), dim3(256), 0, stream>>>(attn, U, qw, qb,
                                                        out, out + 2097152);
}